// Round 5
// baseline (351.653 us; speedup 1.0000x reference)
//
#include <hip/hip_runtime.h>
#include <cstdint>
#include <math.h>

#define B_ 64
#define S_ 512
#define H_ 1024
#define T_ 24

typedef unsigned int u32;
// async global->LDS DMA, 16B per lane. LDS dest = wave-uniform base + lane*16.
#define GLD_LDS16(g, l)                                                        \
    __builtin_amdgcn_global_load_lds(                                          \
        (const __attribute__((address_space(1))) u32*)(g),                     \
        (__attribute__((address_space(3))) u32*)(l), 16, 0, 0)

// readlane: value from lane `sl` (wave-uniform index ok), bitcast through uint
__device__ __forceinline__ float rl_f32(float x, int sl) {
    return __uint_as_float(__builtin_amdgcn_readlane(__float_as_uint(x), sl));
}

// ---------------------------------------------------------------------------
// Kernel 1: emission[b,s,t] = sum_h feats[b,s,h]*W[t,h] + bias[t]
// 512 blocks x 512 thr (8 waves). Block owns 64 rows; wave w owns t-trio
// [3w,3w+3) for all 64 rows (lane = row). feats staged via global_load_lds
// (16B) double-buffered, float4-column-major (conflict-free both ways).
// W: preloaded ONCE into 48 VGPRs/lane (lane l holds W[t0+t][l*16+m]);
// K-loop reads W via v_readlane (reg idx (i&3)*4+e compile-time, lane idx
// 4c+(i>>2) wave-uniform SGPR). R4 post-mortem: in-loop s_load of W mixed
// SMEM+LDS on lgkmcnt -> OOO SMEM forces lgkmcnt(0) waits -> 80% stall
// (VALUBusy 19%). Pure-LDS loop restores fine-grained lgkmcnt(N) pipelining.
// ---------------------------------------------------------------------------
__global__ __launch_bounds__(512) void gemm_kernel(const float* __restrict__ feats,
                                                   const float* __restrict__ W,
                                                   const float* __restrict__ bias,
                                                   float* __restrict__ emission) {
    __shared__ float4 tile4[2][1024];   // 2 x 16KB chunk buffers (64 rows x 64 h)
    const int tid  = threadIdx.x;
    const int lane = tid & 63;                                   // = row in block
    const int w    = __builtin_amdgcn_readfirstlane(tid >> 6);   // wave 0..7
    const int t0   = w * 3;
    const long row0 = (long)blockIdx.x * 64;
    const float* fbase = feats + row0 * H_;

    // Per-lane W cache: lane l, reg m -> W[t0+t][l*16+m]  (48 VGPRs)
    float Wreg[3][16];
#pragma unroll
    for (int t = 0; t < 3; ++t) {
        const float* wr = W + (long)(t0 + t) * H_ + lane * 16;
#pragma unroll
        for (int m4 = 0; m4 < 4; ++m4) {
            const float4 v = *(const float4*)(wr + m4 * 4);
            Wreg[t][m4 * 4 + 0] = v.x;
            Wreg[t][m4 * 4 + 1] = v.y;
            Wreg[t][m4 * 4 + 2] = v.z;
            Wreg[t][m4 * 4 + 3] = v.w;
        }
    }

    // wave w stages float4-columns c4 = 2w, 2w+1 of each chunk
    const float* g0 = fbase + (long)lane * H_ + (2 * w) * 4;
    const float* g1 = g0 + 4;
#define STAGE(c, buf)                                                          \
    do {                                                                       \
        GLD_LDS16(g0 + (c) * 64, &tile4[(buf)][(2 * w) * 64]);                 \
        GLD_LDS16(g1 + (c) * 64, &tile4[(buf)][(2 * w + 1) * 64]);             \
    } while (0)

    float acc[3] = {0.f, 0.f, 0.f};
    STAGE(0, 0);

    for (int c = 0; c < 16; ++c) {
        __syncthreads();                 // vmcnt(0)+barrier: DMA for buf c&1 done
        if (c + 1 < 16) STAGE(c + 1, (c + 1) & 1);
        const float4* tb = tile4[c & 1];
#pragma unroll
        for (int i = 0; i < 16; ++i) {
            const float4 fv = tb[i * 64 + lane];
            const int sl = 4 * c + (i >> 2);     // source lane (wave-uniform)
            const int m = (i & 3) * 4;           // compile-time reg index
#pragma unroll
            for (int t = 0; t < 3; ++t) {
                acc[t] = fmaf(fv.x, rl_f32(Wreg[t][m + 0], sl), acc[t]);
                acc[t] = fmaf(fv.y, rl_f32(Wreg[t][m + 1], sl), acc[t]);
                acc[t] = fmaf(fv.z, rl_f32(Wreg[t][m + 2], sl), acc[t]);
                acc[t] = fmaf(fv.w, rl_f32(Wreg[t][m + 3], sl), acc[t]);
            }
        }
    }

    float* out = emission + (row0 + lane) * T_ + t0;
#pragma unroll
    for (int t = 0; t < 3; ++t) out[t] = acc[t] + bias[t0 + t];
#undef STAGE
}

// ---------------------------------------------------------------------------
// Kernel 2: gold-path score per batch. One wave per batch.
// ---------------------------------------------------------------------------
__global__ __launch_bounds__(64) void score_kernel(const float* __restrict__ emission,
                                                   const int* __restrict__ target,
                                                   const int* __restrict__ mask,
                                                   const float* __restrict__ trans,
                                                   float* __restrict__ ws_score) {
    const int b = blockIdx.x;
    const int lane = threadIdx.x;
    float sum = 0.f;
    for (int s = lane; s < S_; s += 64) {
        if (mask[b * S_ + s]) {
            const int tg = target[b * S_ + s];
            float v = emission[((long)b * S_ + s) * T_ + tg];
            if (s > 0) v += trans[target[b * S_ + s - 1] * T_ + tg];
            sum += v;
        }
    }
#pragma unroll
    for (int off = 32; off; off >>= 1) sum += __shfl_down(sum, off);
    if (lane == 0) ws_score[b] = sum;
}

// ---------------------------------------------------------------------------
// Kernel 3: forward algorithm, PURE probability domain. One wave per batch.
// q'_j = (sum_i q_i E_ij) * X_j, X = exp(emit) precomputed in the prefetch
// ring (OFF the critical chain). No exp/log per step. Renormalize once per
// 16 steps: growth <= 24^16 * e^{±14} stays in [1e13, 2e28] -- safe in fp32
// (overflow would need a 16-sigma emission sum; never). C += log(r) keeps
// logZ exact. Critical path/step: readlane + 6-deep FMA + adds + mul ~44cyc.
// (R3 lesson: any constant-renorm scheme must bound drift; here drift is
// bounded BY CONSTRUCTION inside each 16-step window, and the window renorm
// uses the actual computed q -> zero long-term drift.)
// ---------------------------------------------------------------------------
__global__ __launch_bounds__(64) void scan_kernel(const float* __restrict__ emission,
                                                  const int* __restrict__ mask,
                                                  const float* __restrict__ trans,
                                                  float* __restrict__ ws_logZ) {
    const int b = blockIdx.x;
    const int j = threadIdx.x;          // math lanes j<24; others dummies
    const int jj = j < 24 ? j : 23;

    const float* em = emission + (long)b * S_ * T_;
    const int* mk = mask + b * S_;

    // len = sum(mask row) (prefix-contiguous by construction)
    int mc = 0;
#pragma unroll
    for (int k = 0; k < 8; ++k) mc += mk[j + k * 64];
#pragma unroll
    for (int off = 32; off; off >>= 1) mc += __shfl_xor(mc, off);
    const int len = __builtin_amdgcn_readfirstlane(mc);

    float E[24];
#pragma unroll
    for (int i = 0; i < 24; ++i) E[i] = __expf(trans[i * T_ + jj]);

    float q = (j < 24) ? __expf(em[j]) : 0.f;
    float C = 0.f;

    // prefetch ring of X = exp(emission), depth 16
    float xbuf[16];
#pragma unroll
    for (int k = 0; k < 16; ++k) xbuf[k] = __expf(em[(1 + k) * T_ + jj]);

    for (int sb = 1; sb < S_; sb += 16) {
#pragma unroll
        for (int k = 0; k < 16; ++k) {
            const int s = sb + k;
            const float X = xbuf[k];
            const int sp = s + 16;
            const float nl = (sp < S_) ? em[sp * T_ + jj] : 0.f;
            xbuf[k] = __expf(nl);        // off-chain: needed 16 steps later

            if (s < len) {               // uniform branch (len in SGPR)
                float s0 = 0.f, s1 = 0.f, s2 = 0.f, s3 = 0.f;
#pragma unroll
                for (int i = 0; i < 24; i += 4) {
                    s0 = fmaf(rl_f32(q, i + 0), E[i + 0], s0);
                    s1 = fmaf(rl_f32(q, i + 1), E[i + 1], s1);
                    s2 = fmaf(rl_f32(q, i + 2), E[i + 2], s2);
                    s3 = fmaf(rl_f32(q, i + 3), E[i + 3], s3);
                }
                q = ((s0 + s1) + (s2 + s3)) * X;
            }
        }
        // window renormalization (1/16 amortized on the chain)
        const float r = rl_f32(q, 0);
        q *= (1.0f / r);
        C += __logf(r);
    }

    float ex = (j < 24) ? q : 0.f;
#pragma unroll
    for (int off = 32; off; off >>= 1) ex += __shfl_down(ex, off);
    if (j == 0) ws_logZ[b] = C + __logf(ex);
}

// ---------------------------------------------------------------------------
// Kernel 4: loss = -mean(score - logZ)
// ---------------------------------------------------------------------------
__global__ __launch_bounds__(64) void finalize_kernel(const float* __restrict__ ws_score,
                                                      const float* __restrict__ ws_logZ,
                                                      float* __restrict__ out) {
    const int l = threadIdx.x;
    float v = ws_score[l] - ws_logZ[l];
#pragma unroll
    for (int off = 32; off; off >>= 1) v += __shfl_down(v, off);
    if (l == 0) out[0] = -v * (1.0f / B_);
}

extern "C" void kernel_launch(void* const* d_in, const int* in_sizes, int n_in,
                              void* d_out, int out_size, void* d_ws, size_t ws_size,
                              hipStream_t stream) {
    const float* feats  = (const float*)d_in[0];
    const int*   target = (const int*)d_in[1];
    const int*   mask   = (const int*)d_in[2];
    const float* W      = (const float*)d_in[3];
    const float* bias   = (const float*)d_in[4];
    const float* trans  = (const float*)d_in[5];

    float* out = (float*)d_out;
    float* emission = out + 1;            // output 1, written in place
    float* ws_score = (float*)d_ws;       // 64 floats
    float* ws_logZ  = ws_score + 64;      // 64 floats

    gemm_kernel<<<512, 512, 0, stream>>>(feats, W, bias, emission);
    score_kernel<<<64, 64, 0, stream>>>(emission, target, mask, trans, ws_score);
    scan_kernel<<<64, 64, 0, stream>>>(emission, mask, trans, ws_logZ);
    finalize_kernel<<<1, 64, 0, stream>>>(ws_score, ws_logZ, out);
}

// Round 6
// 323.610 us; speedup vs baseline: 1.0867x; 1.0867x over previous
//
#include <hip/hip_runtime.h>
#include <cstdint>
#include <math.h>

#define B_ 64
#define S_ 512
#define H_ 1024
#define T_ 24

typedef unsigned int u32;
// async global->LDS DMA, 16B per lane. LDS dest = wave-uniform base + lane*16.
#define GLD_LDS16(g, l)                                                        \
    __builtin_amdgcn_global_load_lds(                                          \
        (const __attribute__((address_space(1))) u32*)(g),                     \
        (__attribute__((address_space(3))) u32*)(l), 16, 0, 0)

// readlane: value from lane `sl` (wave-uniform index ok), bitcast through uint
__device__ __forceinline__ float rl_f32(float x, int sl) {
    return __uint_as_float(__builtin_amdgcn_readlane(__float_as_uint(x), sl));
}

// ---------------------------------------------------------------------------
// Kernel 1: emission[b,s,t] = sum_h feats[b,s,h]*W[t,h] + bias[t]
// 512 blocks x 512 thr (8 waves). Block owns 64 rows; wave w owns t-trio
// [3w,3w+3) for all 64 rows (lane = row). feats staged via global_load_lds
// (16B) double-buffered, float4-column-major (conflict-free both ways).
// W preloaded into 48 VGPRs/lane; K-loop reads W via v_readlane (pure-LDS
// lgkmcnt in the loop -- R4 lesson: never mix s_load with ds_read).
// __launch_bounds__(512,4): cap 128 VGPR (need ~75) -- R5 lesson: without
// the min-waves hint the allocator starved us to 36 VGPR and spilled.
// ---------------------------------------------------------------------------
__global__ __launch_bounds__(512, 4) void gemm_kernel(const float* __restrict__ feats,
                                                      const float* __restrict__ W,
                                                      const float* __restrict__ bias,
                                                      float* __restrict__ emission) {
    __shared__ float4 tile4[2][1024];   // 2 x 16KB chunk buffers (64 rows x 64 h)
    const int tid  = threadIdx.x;
    const int lane = tid & 63;                                   // = row in block
    const int w    = __builtin_amdgcn_readfirstlane(tid >> 6);   // wave 0..7
    const int t0   = w * 3;
    const long row0 = (long)blockIdx.x * 64;
    const float* fbase = feats + row0 * H_;

    // Per-lane W cache: lane l, reg m -> W[t0+t][l*16+m]  (48 VGPRs)
    float Wreg[3][16];
#pragma unroll
    for (int t = 0; t < 3; ++t) {
        const float* wr = W + (long)(t0 + t) * H_ + lane * 16;
#pragma unroll
        for (int m4 = 0; m4 < 4; ++m4) {
            const float4 v = *(const float4*)(wr + m4 * 4);
            Wreg[t][m4 * 4 + 0] = v.x;
            Wreg[t][m4 * 4 + 1] = v.y;
            Wreg[t][m4 * 4 + 2] = v.z;
            Wreg[t][m4 * 4 + 3] = v.w;
        }
    }

    // wave w stages float4-columns c4 = 2w, 2w+1 of each chunk
    const float* g0 = fbase + (long)lane * H_ + (2 * w) * 4;
    const float* g1 = g0 + 4;
#define STAGE(c, buf)                                                          \
    do {                                                                       \
        GLD_LDS16(g0 + (c) * 64, &tile4[(buf)][(2 * w) * 64]);                 \
        GLD_LDS16(g1 + (c) * 64, &tile4[(buf)][(2 * w + 1) * 64]);             \
    } while (0)

    float acc[3] = {0.f, 0.f, 0.f};
    STAGE(0, 0);

    for (int c = 0; c < 16; ++c) {
        __syncthreads();                 // vmcnt(0)+barrier: DMA for buf c&1 done
        if (c + 1 < 16) STAGE(c + 1, (c + 1) & 1);
        const float4* tb = tile4[c & 1];
#pragma unroll
        for (int i = 0; i < 16; ++i) {
            const float4 fv = tb[i * 64 + lane];
            const int sl = 4 * c + (i >> 2);     // source lane (wave-uniform)
            const int m = (i & 3) * 4;           // compile-time reg index
#pragma unroll
            for (int t = 0; t < 3; ++t) {
                acc[t] = fmaf(fv.x, rl_f32(Wreg[t][m + 0], sl), acc[t]);
                acc[t] = fmaf(fv.y, rl_f32(Wreg[t][m + 1], sl), acc[t]);
                acc[t] = fmaf(fv.z, rl_f32(Wreg[t][m + 2], sl), acc[t]);
                acc[t] = fmaf(fv.w, rl_f32(Wreg[t][m + 3], sl), acc[t]);
            }
        }
    }

    float* out = emission + (row0 + lane) * T_ + t0;
#pragma unroll
    for (int t = 0; t < 3; ++t) out[t] = acc[t] + bias[t0 + t];
#undef STAGE
}

// ---------------------------------------------------------------------------
// Kernel 2: gold-path score per batch. One wave per batch.
// ---------------------------------------------------------------------------
__global__ __launch_bounds__(64) void score_kernel(const float* __restrict__ emission,
                                                   const int* __restrict__ target,
                                                   const int* __restrict__ mask,
                                                   const float* __restrict__ trans,
                                                   float* __restrict__ ws_score) {
    const int b = blockIdx.x;
    const int lane = threadIdx.x;
    float sum = 0.f;
    for (int s = lane; s < S_; s += 64) {
        if (mask[b * S_ + s]) {
            const int tg = target[b * S_ + s];
            float v = emission[((long)b * S_ + s) * T_ + tg];
            if (s > 0) v += trans[target[b * S_ + s - 1] * T_ + tg];
            sum += v;
        }
    }
#pragma unroll
    for (int off = 32; off; off >>= 1) sum += __shfl_down(sum, off);
    if (lane == 0) ws_score[b] = sum;
}

// ---------------------------------------------------------------------------
// Kernel 3: forward algorithm, pure probability domain. One wave per batch.
// q'_j = (sum_i q_i E_ij) * X_j, X = exp(emit) precomputed off-chain in an
// 8-deep prefetch ring. Renorm once per 16 steps by actual q (zero drift;
// bounded in-window by construction: 24^16 * e^{±14} fits fp32).
// __launch_bounds__(64,1): R5 lesson -- allocator capped us at 36 VGPR and
// spilled E[24]+ring to scratch => 680 cyc/step. Live state now ~45 VGPR.
// ---------------------------------------------------------------------------
__global__ __launch_bounds__(64, 1) void scan_kernel(const float* __restrict__ emission,
                                                     const int* __restrict__ mask,
                                                     const float* __restrict__ trans,
                                                     float* __restrict__ ws_logZ) {
    const int b = blockIdx.x;
    const int j = threadIdx.x;          // math lanes j<24; others dummies
    const int jj = j < 24 ? j : 23;

    const float* em = emission + (long)b * S_ * T_;
    const int* mk = mask + b * S_;

    // len = sum(mask row) (prefix-contiguous by construction)
    int mc = 0;
#pragma unroll
    for (int k = 0; k < 8; ++k) mc += mk[j + k * 64];
#pragma unroll
    for (int off = 32; off; off >>= 1) mc += __shfl_xor(mc, off);
    const int len = __builtin_amdgcn_readfirstlane(mc);

    float E[24];
#pragma unroll
    for (int i = 0; i < 24; ++i) E[i] = __expf(trans[i * T_ + jj]);

    float q = (j < 24) ? __expf(em[j]) : 0.f;
    float C = 0.f;

    // prefetch ring of X = exp(emission), depth 8 (~440cyc lookahead at
    // ~55cyc/step -- covers L2/L3 latency for the freshly-written emission)
    float xbuf[8];
#pragma unroll
    for (int k = 0; k < 8; ++k) xbuf[k] = __expf(em[(1 + k) * T_ + jj]);

    for (int sb = 1; sb < S_; sb += 16) {
#pragma unroll
        for (int k = 0; k < 16; ++k) {
            const int s = sb + k;
            const float X = xbuf[k & 7];
            const int sp = s + 8;
            const float nl = (sp < S_) ? em[sp * T_ + jj] : 0.f;
            xbuf[k & 7] = __expf(nl);    // off-chain: needed 8 steps later

            if (s < len) {               // uniform branch (len in SGPR)
                float s0 = 0.f, s1 = 0.f, s2 = 0.f, s3 = 0.f;
#pragma unroll
                for (int i = 0; i < 24; i += 4) {
                    s0 = fmaf(rl_f32(q, i + 0), E[i + 0], s0);
                    s1 = fmaf(rl_f32(q, i + 1), E[i + 1], s1);
                    s2 = fmaf(rl_f32(q, i + 2), E[i + 2], s2);
                    s3 = fmaf(rl_f32(q, i + 3), E[i + 3], s3);
                }
                q = ((s0 + s1) + (s2 + s3)) * X;
            }
        }
        // window renormalization (1/16 amortized on the chain)
        const float r = rl_f32(q, 0);
        q *= (1.0f / r);
        C += __logf(r);
    }

    float ex = (j < 24) ? q : 0.f;
#pragma unroll
    for (int off = 32; off; off >>= 1) ex += __shfl_down(ex, off);
    if (j == 0) ws_logZ[b] = C + __logf(ex);
}

// ---------------------------------------------------------------------------
// Kernel 4: loss = -mean(score - logZ)
// ---------------------------------------------------------------------------
__global__ __launch_bounds__(64) void finalize_kernel(const float* __restrict__ ws_score,
                                                      const float* __restrict__ ws_logZ,
                                                      float* __restrict__ out) {
    const int l = threadIdx.x;
    float v = ws_score[l] - ws_logZ[l];
#pragma unroll
    for (int off = 32; off; off >>= 1) v += __shfl_down(v, off);
    if (l == 0) out[0] = -v * (1.0f / B_);
}

extern "C" void kernel_launch(void* const* d_in, const int* in_sizes, int n_in,
                              void* d_out, int out_size, void* d_ws, size_t ws_size,
                              hipStream_t stream) {
    const float* feats  = (const float*)d_in[0];
    const int*   target = (const int*)d_in[1];
    const int*   mask   = (const int*)d_in[2];
    const float* W      = (const float*)d_in[3];
    const float* bias   = (const float*)d_in[4];
    const float* trans  = (const float*)d_in[5];

    float* out = (float*)d_out;
    float* emission = out + 1;            // output 1, written in place
    float* ws_score = (float*)d_ws;       // 64 floats
    float* ws_logZ  = ws_score + 64;      // 64 floats

    gemm_kernel<<<512, 512, 0, stream>>>(feats, W, bias, emission);
    score_kernel<<<64, 64, 0, stream>>>(emission, target, mask, trans, ws_score);
    scan_kernel<<<64, 64, 0, stream>>>(emission, mask, trans, ws_logZ);
    finalize_kernel<<<1, 64, 0, stream>>>(ws_score, ws_logZ, out);
}

// Round 7
// 307.274 us; speedup vs baseline: 1.1444x; 1.0532x over previous
//
#include <hip/hip_runtime.h>
#include <cstdint>
#include <math.h>

#define B_ 64
#define S_ 512
#define H_ 1024
#define T_ 24

typedef unsigned int u32;
// async global->LDS DMA, 16B per lane. LDS dest = wave-uniform base + lane*16.
#define GLD_LDS16(g, l)                                                        \
    __builtin_amdgcn_global_load_lds(                                          \
        (const __attribute__((address_space(1))) u32*)(g),                     \
        (__attribute__((address_space(3))) u32*)(l), 16, 0, 0)

// readlane: value from lane `sl` (wave-uniform index ok), bitcast through uint
__device__ __forceinline__ float rl_f32(float x, int sl) {
    return __uint_as_float(__builtin_amdgcn_readlane(__float_as_uint(x), sl));
}

// ---------------------------------------------------------------------------
// Kernel 1: emission GEMM (unchanged from R6). 512x512, DMA-staged feats,
// W in 48 VGPRs/lane read back via v_readlane, pure-LDS K-loop lgkmcnt.
// ---------------------------------------------------------------------------
__global__ __launch_bounds__(512, 4) void gemm_kernel(const float* __restrict__ feats,
                                                      const float* __restrict__ W,
                                                      const float* __restrict__ bias,
                                                      float* __restrict__ emission) {
    __shared__ float4 tile4[2][1024];   // 2 x 16KB chunk buffers (64 rows x 64 h)
    const int tid  = threadIdx.x;
    const int lane = tid & 63;                                   // = row in block
    const int w    = __builtin_amdgcn_readfirstlane(tid >> 6);   // wave 0..7
    const int t0   = w * 3;
    const long row0 = (long)blockIdx.x * 64;
    const float* fbase = feats + row0 * H_;

    // Per-lane W cache: lane l, reg m -> W[t0+t][l*16+m]  (48 VGPRs)
    float Wreg[3][16];
#pragma unroll
    for (int t = 0; t < 3; ++t) {
        const float* wr = W + (long)(t0 + t) * H_ + lane * 16;
#pragma unroll
        for (int m4 = 0; m4 < 4; ++m4) {
            const float4 v = *(const float4*)(wr + m4 * 4);
            Wreg[t][m4 * 4 + 0] = v.x;
            Wreg[t][m4 * 4 + 1] = v.y;
            Wreg[t][m4 * 4 + 2] = v.z;
            Wreg[t][m4 * 4 + 3] = v.w;
        }
    }

    // wave w stages float4-columns c4 = 2w, 2w+1 of each chunk
    const float* g0 = fbase + (long)lane * H_ + (2 * w) * 4;
    const float* g1 = g0 + 4;
#define STAGE(c, buf)                                                          \
    do {                                                                       \
        GLD_LDS16(g0 + (c) * 64, &tile4[(buf)][(2 * w) * 64]);                 \
        GLD_LDS16(g1 + (c) * 64, &tile4[(buf)][(2 * w + 1) * 64]);             \
    } while (0)

    float acc[3] = {0.f, 0.f, 0.f};
    STAGE(0, 0);

    for (int c = 0; c < 16; ++c) {
        __syncthreads();                 // vmcnt(0)+barrier: DMA for buf c&1 done
        if (c + 1 < 16) STAGE(c + 1, (c + 1) & 1);
        const float4* tb = tile4[c & 1];
#pragma unroll
        for (int i = 0; i < 16; ++i) {
            const float4 fv = tb[i * 64 + lane];
            const int sl = 4 * c + (i >> 2);     // source lane (wave-uniform)
            const int m = (i & 3) * 4;           // compile-time reg index
#pragma unroll
            for (int t = 0; t < 3; ++t) {
                acc[t] = fmaf(fv.x, rl_f32(Wreg[t][m + 0], sl), acc[t]);
                acc[t] = fmaf(fv.y, rl_f32(Wreg[t][m + 1], sl), acc[t]);
                acc[t] = fmaf(fv.z, rl_f32(Wreg[t][m + 2], sl), acc[t]);
                acc[t] = fmaf(fv.w, rl_f32(Wreg[t][m + 3], sl), acc[t]);
            }
        }
    }

    float* out = emission + (row0 + lane) * T_ + t0;
#pragma unroll
    for (int t = 0; t < 3; ++t) out[t] = acc[t] + bias[t0 + t];
#undef STAGE
}

// ---------------------------------------------------------------------------
// Kernel 2: gold-path score per batch. One wave per batch.
// ---------------------------------------------------------------------------
__global__ __launch_bounds__(64) void score_kernel(const float* __restrict__ emission,
                                                   const int* __restrict__ target,
                                                   const int* __restrict__ mask,
                                                   const float* __restrict__ trans,
                                                   float* __restrict__ ws_score) {
    const int b = blockIdx.x;
    const int lane = threadIdx.x;
    float sum = 0.f;
    for (int s = lane; s < S_; s += 64) {
        if (mask[b * S_ + s]) {
            const int tg = target[b * S_ + s];
            float v = emission[((long)b * S_ + s) * T_ + tg];
            if (s > 0) v += trans[target[b * S_ + s - 1] * T_ + tg];
            sum += v;
        }
    }
#pragma unroll
    for (int off = 32; off; off >>= 1) sum += __shfl_down(sum, off);
    if (lane == 0) ws_score[b] = sum;
}

// ---------------------------------------------------------------------------
// Kernel 3: forward algorithm, pure probability domain. One wave per batch.
// R6 post-mortem (VGPR_Count=28): E[24] as an ARRAY was never promoted --
// it lived in scratch, 24 buffer-loads per step ~490cyc. Fix 1: E as 24
// individually-named scalars (cannot be aggregate-demoted). Fix 2: the ring
// holds RAW emission loads (exp at consume time) so loads get a true 8-step
// lead; R6 exp'd at load time => zero prefetch distance on the load itself.
// Renorm once/16 steps by actual q (zero drift; 24^16*e^14 fits fp32).
// ---------------------------------------------------------------------------
#define DECL_E(i) const float E##i = __expf(trans[(i) * T_ + jj]);
#define FMA4(i0, i1, i2, i3)                                                   \
    s0 = fmaf(rl_f32(q, i0), E##i0, s0);                                       \
    s1 = fmaf(rl_f32(q, i1), E##i1, s1);                                       \
    s2 = fmaf(rl_f32(q, i2), E##i2, s2);                                       \
    s3 = fmaf(rl_f32(q, i3), E##i3, s3);

__global__ __launch_bounds__(64, 1) void scan_kernel(const float* __restrict__ emission,
                                                     const int* __restrict__ mask,
                                                     const float* __restrict__ trans,
                                                     float* __restrict__ ws_logZ) {
    const int b = blockIdx.x;
    const int j = threadIdx.x;          // math lanes j<24; others dummies
    const int jj = j < 24 ? j : 23;

    const float* em = emission + (long)b * S_ * T_;
    const int* mk = mask + b * S_;

    // len = sum(mask row) (prefix-contiguous by construction)
    int mc = 0;
#pragma unroll
    for (int k = 0; k < 8; ++k) mc += mk[j + k * 64];
#pragma unroll
    for (int off = 32; off; off >>= 1) mc += __shfl_xor(mc, off);
    const int len = __builtin_amdgcn_readfirstlane(mc);

    DECL_E(0)  DECL_E(1)  DECL_E(2)  DECL_E(3)  DECL_E(4)  DECL_E(5)
    DECL_E(6)  DECL_E(7)  DECL_E(8)  DECL_E(9)  DECL_E(10) DECL_E(11)
    DECL_E(12) DECL_E(13) DECL_E(14) DECL_E(15) DECL_E(16) DECL_E(17)
    DECL_E(18) DECL_E(19) DECL_E(20) DECL_E(21) DECL_E(22) DECL_E(23)

    float q = (j < 24) ? __expf(em[j]) : 0.f;
    float C = 0.f;

    // prefetch ring of RAW emissions, depth 8 (load leads consume by 8 steps)
    float lb[8];
#pragma unroll
    for (int k = 0; k < 8; ++k) lb[k] = em[(1 + k) * T_ + jj];

    for (int sb = 1; sb < S_; sb += 16) {
#pragma unroll
        for (int k = 0; k < 16; ++k) {
            const int s = sb + k;
            const float X = __expf(lb[k & 7]);   // loaded 8 steps ago: no stall
            const int sp = s + 8;
            lb[k & 7] = (sp < S_) ? em[sp * T_ + jj] : 0.f;

            if (s < len) {               // uniform branch (len in SGPR)
                float s0 = 0.f, s1 = 0.f, s2 = 0.f, s3 = 0.f;
                FMA4(0, 1, 2, 3)
                FMA4(4, 5, 6, 7)
                FMA4(8, 9, 10, 11)
                FMA4(12, 13, 14, 15)
                FMA4(16, 17, 18, 19)
                FMA4(20, 21, 22, 23)
                q = ((s0 + s1) + (s2 + s3)) * X;
            }
        }
        // window renormalization (1/16 amortized on the chain)
        const float r = rl_f32(q, 0);
        q *= (1.0f / r);
        C += __logf(r);
    }

    float ex = (j < 24) ? q : 0.f;
#pragma unroll
    for (int off = 32; off; off >>= 1) ex += __shfl_down(ex, off);
    if (j == 0) ws_logZ[b] = C + __logf(ex);
}

// ---------------------------------------------------------------------------
// Kernel 4: loss = -mean(score - logZ)
// ---------------------------------------------------------------------------
__global__ __launch_bounds__(64) void finalize_kernel(const float* __restrict__ ws_score,
                                                      const float* __restrict__ ws_logZ,
                                                      float* __restrict__ out) {
    const int l = threadIdx.x;
    float v = ws_score[l] - ws_logZ[l];
#pragma unroll
    for (int off = 32; off; off >>= 1) v += __shfl_down(v, off);
    if (l == 0) out[0] = -v * (1.0f / B_);
}

extern "C" void kernel_launch(void* const* d_in, const int* in_sizes, int n_in,
                              void* d_out, int out_size, void* d_ws, size_t ws_size,
                              hipStream_t stream) {
    const float* feats  = (const float*)d_in[0];
    const int*   target = (const int*)d_in[1];
    const int*   mask   = (const int*)d_in[2];
    const float* W      = (const float*)d_in[3];
    const float* bias   = (const float*)d_in[4];
    const float* trans  = (const float*)d_in[5];

    float* out = (float*)d_out;
    float* emission = out + 1;            // output 1, written in place
    float* ws_score = (float*)d_ws;       // 64 floats
    float* ws_logZ  = ws_score + 64;      // 64 floats

    gemm_kernel<<<512, 512, 0, stream>>>(feats, W, bias, emission);
    score_kernel<<<64, 64, 0, stream>>>(emission, target, mask, trans, ws_score);
    scan_kernel<<<64, 64, 0, stream>>>(emission, mask, trans, ws_logZ);
    finalize_kernel<<<1, 64, 0, stream>>>(ws_score, ws_logZ, out);
}